// Round 1
// baseline (108.297 us; speedup 1.0000x reference)
//
#include <hip/hip_runtime.h>

// Problem constants (from reference): B=8, C=256, O=8, H=W=64, G=8
#define BB   8
#define CC   256
#define OO   8
#define GG   8
#define HW   4096        // 64*64
#define CPG  32          // C / G

// Block: 256 threads, each owns 4 consecutive hw elements (float4).
// Each block covers one (b, c) and a 1024-element hw tile.
// Grid: B * (HW/1024) * C = 8 * 4 * 256 = 8192 blocks; c is the fastest
// grid dim so concurrently-resident blocks share offset reads in L2.
__global__ __launch_bounds__(256) void deo_kernel(const float* __restrict__ x,
                                                  const float* __restrict__ off,
                                                  float* __restrict__ out) {
    // Transposed staging: lds[(o*4 + j)*256 + tid]. Each thread writes and
    // reads ONLY its own column (index tid) -> no __syncthreads needed.
    // Read bank = tid & 31 -> conflict-free.
    __shared__ float lds[OO * 4 * 256];

    const int tid = threadIdx.x;
    const int bid = blockIdx.x;

    const int c    = bid & 255;        // fastest: channels share offsets
    const int bt   = bid >> 8;
    const int tile = bt & 3;           // which 1024-elem hw tile
    const int b    = bt >> 2;
    const int g    = c >> 5;           // c / CPG

    const int hw0 = tile * 1024 + tid * 4;

    const float* xp = x   + ((size_t)(b * CC + c)) * (OO * HW) + hw0;
    const float* op = off + ((size_t)(b * GG + g)) * (OO * HW) + hw0;
    float*       yp = out + ((size_t)(b * CC + c)) * (OO * HW) + hw0;

    // ---- stage x into LDS (transposed) ----
#pragma unroll
    for (int o = 0; o < OO; ++o) {
        const float4 v = *(const float4*)(xp + o * HW);
        lds[(o * 4 + 0) * 256 + tid] = v.x;
        lds[(o * 4 + 1) * 256 + tid] = v.y;
        lds[(o * 4 + 2) * 256 + tid] = v.z;
        lds[(o * 4 + 3) * 256 + tid] = v.w;
    }
    // no barrier: private-column access pattern

    // ---- interpolate and store ----
    auto interp = [&](float offv, int o, int j) -> float {
        const float pv = (float)o + offv;
        const float p0 = floorf(pv);
        const float w1 = pv - p0;
        const int i0 = ((int)p0) & 7;       // cyclic wrap (two's complement AND == mod 8)
        const int i1 = (i0 + 1) & 7;
        const float a  = lds[(i0 * 4 + j) * 256 + tid];
        const float bb = lds[(i1 * 4 + j) * 256 + tid];
        return fmaf(w1, bb - a, a);         // (1-w1)*a + w1*bb
    };

#pragma unroll
    for (int o = 0; o < OO; ++o) {
        const float4 w = *(const float4*)(op + o * HW);
        float4 r;
        r.x = interp(w.x, o, 0);
        r.y = interp(w.y, o, 1);
        r.z = interp(w.z, o, 2);
        r.w = interp(w.w, o, 3);
        *(float4*)(yp + o * HW) = r;
    }
}

extern "C" void kernel_launch(void* const* d_in, const int* in_sizes, int n_in,
                              void* d_out, int out_size, void* d_ws, size_t ws_size,
                              hipStream_t stream) {
    const float* x   = (const float*)d_in[0];
    const float* off = (const float*)d_in[1];
    float*       out = (float*)d_out;

    const int blocks = BB * (HW / 1024) * CC;   // 8192
    deo_kernel<<<blocks, 256, 0, stream>>>(x, off, out);
}